// Round 2
// 731.453 us; speedup vs baseline: 1.0222x; 1.0222x over previous
//
#include <hip/hip_runtime.h>
#include <stdint.h>
#include <stddef.h>

typedef __bf16 bft;
typedef __bf16 bf16x4 __attribute__((ext_vector_type(4)));
typedef __bf16 bf16x8 __attribute__((ext_vector_type(8)));
typedef float f32x4 __attribute__((ext_vector_type(4)));

#define NH 12
#define HD 64
#define SEQ 1025
#define NB 32
#define DMODEL 768
#define MROWS (NB * SEQ)   /* 32800 */
#define BHN (NB * NH)      /* 384 */
#define CSPLIT 8
#define CCHUNK 129         /* ceil(1025/8) */

__device__ __forceinline__ void gl_lds16(const void* g, void* l) {
  __builtin_amdgcn_global_load_lds(
      (const __attribute__((address_space(1))) void*)g,
      (__attribute__((address_space(3))) void*)l, 16, 0, 0);
}

// hardware transpose read: per 16-lane group, lane c elem j gets element (c&3)
// of the 8B chunk addressed by lane (4j + (c>>2)) — i.e. column c of the [4][16]
// row-major bf16 tile when lanes supply base + 8c bytes.
__device__ __forceinline__ bf16x4 ds_tr16(const bft* p, int boff) {
  bf16x4 d;
  asm volatile("ds_read_b64_tr_b16 %0, %1 offset:%2"
               : "=v"(d)
               : "v"((const __attribute__((address_space(3))) bft*)p), "i"(boff)
               : "memory");
  return d;
}

__device__ __forceinline__ void lgkm0() {
  asm volatile("s_waitcnt lgkmcnt(0)" ::: "memory");
}

// ---------------- K0: fp32 -> bf16 cast ----------------
__global__ __launch_bounds__(256) void k_cast(
    const float* __restrict__ S, bft* __restrict__ D, int n4) {
  int i = blockIdx.x * 256 + threadIdx.x;
  if (i < n4) {
    f32x4 v = *(const f32x4*)(S + (size_t)i * 4);
    bf16x4 o;
    o[0] = (bft)v[0]; o[1] = (bft)v[1]; o[2] = (bft)v[2]; o[3] = (bft)v[3];
    *(bf16x4*)(D + (size_t)i * 4) = o;
  }
}

// ---------------- K1: QKV GEMM + fused RoPE + fused feature map ----------------
// grid (257, 18). y/6 = s (0=q,1=k,2=v). Columns 64-aligned to heads.
// LDS tiles XOR-swizzled: LDS slot cb holds global colblock cb^(row&7).
__global__ __launch_bounds__(256) void k_qkv_gemm(
    const bft* __restrict__ X, const bft* __restrict__ W,
    const bft* __restrict__ P,
    const float* __restrict__ FC, const float* __restrict__ FS,
    bft* __restrict__ QKV) {
  __shared__ __align__(16) bft sA[128 * 64];
  __shared__ __align__(16) bft sB[128 * 64];
  __shared__ __align__(16) bft sP[64 * 64];
  const int tid = threadIdx.x;
  const int lane = tid & 63;
  const int lm = lane & 15;
  const int quad = lane >> 4;
  const int wid = tid >> 6;
  const int wm = (wid & 1) << 6;
  const int wn = (wid >> 1) << 6;
  const int m0 = blockIdx.x * 128;
  const int n0 = blockIdx.y * 128;
  const int sw = lm & 7;
  const int o0 = (quad ^ sw) << 3;        // kk=0 swizzled col offset (elements)
  const int o1 = ((4 + quad) ^ sw) << 3;  // kk=1

  // stage projection (64x64) once, swizzled
#pragma unroll
  for (int it = 0; it < 2; it++) {
    int c = it * 256 + tid;
    int row = c >> 3;
    int col = ((c & 7) ^ (row & 7)) << 3;
    gl_lds16(P + row * 64 + col, sP + c * 8);
  }

  f32x4 acc[4][4] = {};

  for (int kt = 0; kt < DMODEL; kt += 64) {
#pragma unroll
    for (int it = 0; it < 4; it++) {
      int c = it * 256 + tid;
      int row = c >> 3;
      int col = ((c & 7) ^ (row & 7)) << 3;
      int ar = m0 + row;
      if (ar >= MROWS) ar = MROWS - 1;
      gl_lds16(X + (size_t)ar * DMODEL + kt + col, sA + c * 8);
      gl_lds16(W + (size_t)(n0 + row) * DMODEL + kt + col, sB + c * 8);
    }
    __syncthreads();
#pragma unroll
    for (int kk = 0; kk < 2; kk++) {
      const int off = kk ? o1 : o0;  // swizzled, kk encoded in o0/o1
      bf16x8 af[4], bb[4];
#pragma unroll
      for (int i = 0; i < 4; i++)
        af[i] = *(const bf16x8*)(sA + (wm + i * 16 + lm) * 64 + off);
#pragma unroll
      for (int j = 0; j < 4; j++)
        bb[j] = *(const bf16x8*)(sB + (wn + j * 16 + lm) * 64 + off);
#pragma unroll
      for (int i = 0; i < 4; i++)
#pragma unroll
        for (int j = 0; j < 4; j++)
          acc[i][j] = __builtin_amdgcn_mfma_f32_16x16x32_bf16(af[i], bb[j], acc[i][j], 0, 0, 0);
    }
    __syncthreads();
  }

  const int s = blockIdx.y / 6;                 // 0=q 1=k 2=v (uniform per block)
  const int h = ((n0 + wn) - s * DMODEL) >> 6;  // head (uniform per wave)

  // per-wave transpose scratch in dead sA: [64 d][16 tok] bf16 = 1KB/wave
  bft* tt = sA + wid * 1024;
  const bft* tl = tt + quad * 128 + lm * 4;  // tr-read base: quad*256B + lm*8B

  if (s < 2) {
#pragma unroll
    for (int i = 0; i < 4; i++) {
      // token indices for the 4 C-rows this lane holds (r dim)
      int nr[4];
#pragma unroll
      for (int r = 0; r < 4; r++) {
        const int mm = m0 + wm + i * 16 + quad * 4 + r;
        const int bb2 = mm / SEQ;
        nr[r] = mm - bb2 * SEQ;
      }
      // RoPE in C-fragment layout on fp32 acc (single bf16 rounding, baseline numerics)
#pragma unroll
      for (int j = 0; j < 4; j++) {
        const int d = j * 16 + lm;
        const int fj = d >> 1;
        bf16x4 w;
#pragma unroll
        for (int r = 0; r < 4; r++) {
          float v = acc[i][j][r];
          float pv = __shfl_xor(v, 1);
          float ov = v;
          if (nr[r] >= 1) {
            float cc = FC[(nr[r] - 1) * 32 + fj];
            float ss = FS[(nr[r] - 1) * 32 + fj];
            ov = (d & 1) ? (pv * ss + v * cc) : (v * cc - pv * ss);
          }
          w[r] = (bft)ov;
        }
        *(bf16x4*)(tt + d * 16 + quad * 4) = w;  // [d][tok] tile, vector b64
      }
      lgkm0();  // same-wave DS in-order; belt+braces

      // tr-read A-fragments: lane gets tok=lm, d = 8*quad+e
      bf16x4 i0a = ds_tr16(tl, 0);     // d = 8q+0..3
      bf16x4 i0b = ds_tr16(tl, 128);   // d = 8q+4..7
      bf16x4 i1a = ds_tr16(tl, 1024);  // d = 32+8q+0..3
      bf16x4 i1b = ds_tr16(tl, 1152);  // d = 32+8q+4..7
      lgkm0();
      __builtin_amdgcn_sched_barrier(0);
      bf16x8 af0, af1;
#pragma unroll
      for (int e = 0; e < 4; e++) {
        af0[e] = i0a[e]; af0[e + 4] = i0b[e];
        af1[e] = i1a[e]; af1[e + 4] = i1b[e];
      }

      // this lane's token for the store phase
      const int m = m0 + wm + i * 16 + lm;
      const int b = m / SEQ;
      const int n = m - b * SEQ;
      const bool valid = (m < MROWS);
      bft* dst = QKV + ((((size_t)s * NB + b) * NH + h) * SEQ + n) * HD;

      // feature MFMA with SWAPPED operands: A=P rows, B=tokens ->
      // output col=lm=token, row=quad*4+r=feature. Store directly, no LDS.
#pragma unroll
      for (int j2 = 0; j2 < 4; j2++) {
        bf16x8 p0 = *(const bf16x8*)(sP + (j2 * 16 + lm) * 64 + o0);
        bf16x8 p1 = *(const bf16x8*)(sP + (j2 * 16 + lm) * 64 + o1);
        f32x4 fa = {0.f, 0.f, 0.f, 0.f};
        fa = __builtin_amdgcn_mfma_f32_16x16x32_bf16(p0, af0, fa, 0, 0, 0);
        fa = __builtin_amdgcn_mfma_f32_16x16x32_bf16(p1, af1, fa, 0, 0, 0);
        bf16x4 o;
#pragma unroll
        for (int r = 0; r < 4; r++) {
          float v = fa[r] * 0.35355339f;  // 64^-0.25
          o[r] = (bft)(fmaxf(v, 0.f) + 1e-6f);
        }
        if (valid) *(bf16x4*)(dst + j2 * 16 + quad * 4) = o;  // feats j2*16+4q..+3
      }
    }
  } else {
    // v path: transpose via tt + tr-read, vectorized b128 stores (single rounding)
#pragma unroll
    for (int i = 0; i < 4; i++) {
      const int m = m0 + wm + i * 16 + lm;
      const int b = m / SEQ;
      const int n = m - b * SEQ;
      const bool valid = (m < MROWS);
#pragma unroll
      for (int j = 0; j < 4; j++) {
        bf16x4 w;
#pragma unroll
        for (int r = 0; r < 4; r++) w[r] = (bft)acc[i][j][r];
        *(bf16x4*)(tt + (j * 16 + lm) * 16 + quad * 4) = w;
      }
      lgkm0();
      bf16x4 v0a = ds_tr16(tl, 0);
      bf16x4 v0b = ds_tr16(tl, 128);
      bf16x4 v1a = ds_tr16(tl, 1024);
      bf16x4 v1b = ds_tr16(tl, 1152);
      lgkm0();
      __builtin_amdgcn_sched_barrier(0);
      if (valid) {
        bft* dst = QKV + ((((size_t)2 * NB + b) * NH + h) * SEQ + n) * HD;
        bf16x8 w0, w1;
#pragma unroll
        for (int e = 0; e < 4; e++) {
          w0[e] = v0a[e]; w0[e + 4] = v0b[e];
          w1[e] = v1a[e]; w1[e + 4] = v1b[e];
        }
        *(bf16x8*)(dst + quad * 8) = w0;
        *(bf16x8*)(dst + 32 + quad * 8) = w1;
      }
    }
  }
}

// ---------------- K3: context += kf^T @ v (seq-split, atomic), fused k_sum ----------------
__global__ __launch_bounds__(256) void k_context(
    const bft* __restrict__ KF, const bft* __restrict__ V,
    float* __restrict__ CTX, float* __restrict__ KSUM) {
  __shared__ float skf[16 * 64];
  __shared__ float sv[16 * 64];
  const int tid = threadIdx.x;
  const int bh = blockIdx.x;
  const int t_begin = blockIdx.y * CCHUNK;
  const int t_end = (t_begin + CCHUNK < SEQ) ? (t_begin + CCHUNK) : SEQ;
  const bft* kf = KF + (size_t)bh * SEQ * HD;
  const bft* vv = V + (size_t)bh * SEQ * HD;
  const int srow = tid >> 4;
  const int scol = (tid & 15) * 4;
  const int f0 = (tid >> 4) * 4;
  const int e0 = (tid & 15) * 4;

  float acc[4][4] = {};
  float ks[4] = {0.f, 0.f, 0.f, 0.f};

  for (int nt = t_begin; nt < t_end; nt += 16) {
    int n = nt + srow;
    f32x4 kq4 = {0.f, 0.f, 0.f, 0.f}, vq4 = {0.f, 0.f, 0.f, 0.f};
    if (n < t_end) {
      bf16x4 a = *(const bf16x4*)(kf + (size_t)n * 64 + scol);
      bf16x4 c = *(const bf16x4*)(vv + (size_t)n * 64 + scol);
#pragma unroll
      for (int e = 0; e < 4; e++) { kq4[e] = (float)a[e]; vq4[e] = (float)c[e]; }
    }
    *(f32x4*)(skf + srow * 64 + scol) = kq4;
    *(f32x4*)(sv + srow * 64 + scol) = vq4;
    __syncthreads();
#pragma unroll
    for (int t4 = 0; t4 < 16; t4++) {
      f32x4 kq = *(const f32x4*)(skf + t4 * 64 + f0);
      f32x4 vq = *(const f32x4*)(sv + t4 * 64 + e0);
#pragma unroll
      for (int i = 0; i < 4; i++) {
        ks[i] += kq[i];
#pragma unroll
        for (int j = 0; j < 4; j++) acc[i][j] += kq[i] * vq[j];
      }
    }
    __syncthreads();
  }

  float* cp = CTX + (size_t)bh * 4096;
#pragma unroll
  for (int i = 0; i < 4; i++)
#pragma unroll
    for (int j = 0; j < 4; j++) atomicAdd(&cp[(f0 + i) * 64 + e0 + j], acc[i][j]);
  if (e0 == 0) {
#pragma unroll
    for (int i = 0; i < 4; i++) atomicAdd(&KSUM[bh * 64 + f0 + i], ks[i]);
  }
}

// ---------------- K4: out = (qf @ ctx) * (1/(qf . ksum)), write attn(b,n,h*64+e) ----------------
__global__ __launch_bounds__(256) void k_qside(
    const bft* __restrict__ QF, const float* __restrict__ CTX,
    const float* __restrict__ KSUM, bft* __restrict__ ATTN) {
  __shared__ float sqf[128 * 65];
  __shared__ float sctx[64 * 64];
  __shared__ float sks[64];
  const int tid = threadIdx.x;
  const int bh = blockIdx.x;
  const int n0 = blockIdx.y * 128;
  const int ntok = (SEQ - n0 < 128) ? (SEQ - n0) : 128;
  const bft* qf = QF + ((size_t)bh * SEQ + n0) * HD;

#pragma unroll
  for (int i = 0; i < 4; i++) {
    int idx = i * 1024 + tid * 4;
    *(f32x4*)(sctx + idx) = *(const f32x4*)(CTX + (size_t)bh * 4096 + idx);
  }
  if (tid < 64) sks[tid] = KSUM[bh * 64 + tid];

#pragma unroll
  for (int it = 0; it < 4; it++) {
    int c = it * 256 + tid;
    int row = c >> 3;
    int col = (c & 7) << 3;
    if (row < ntok) {
      bf16x8 t = *(const bf16x8*)(qf + (size_t)row * 64 + col);
#pragma unroll
      for (int e = 0; e < 8; e++) sqf[row * 65 + col + e] = (float)t[e];
    } else {
#pragma unroll
      for (int e = 0; e < 8; e++) sqf[row * 65 + col + e] = 0.f;
    }
  }
  __syncthreads();

  const int e0 = (tid & 7) * 8;
  const int t0 = (tid >> 3) * 4;
  float acc[4][8] = {};
  float den[4] = {0.f, 0.f, 0.f, 0.f};
#pragma unroll 8
  for (int f = 0; f < 64; f++) {
    float kv = sks[f];
    f32x4 c0 = *(const f32x4*)(sctx + f * 64 + e0);
    f32x4 c1 = *(const f32x4*)(sctx + f * 64 + e0 + 4);
#pragma unroll
    for (int tk = 0; tk < 4; tk++) {
      float qv = sqf[(t0 + tk) * 65 + f];
      den[tk] += qv * kv;
      acc[tk][0] += qv * c0[0];
      acc[tk][1] += qv * c0[1];
      acc[tk][2] += qv * c0[2];
      acc[tk][3] += qv * c0[3];
      acc[tk][4] += qv * c1[0];
      acc[tk][5] += qv * c1[1];
      acc[tk][6] += qv * c1[2];
      acc[tk][7] += qv * c1[3];
    }
  }
  const int b = bh / NH;
  const int h = bh - b * NH;
#pragma unroll
  for (int tk = 0; tk < 4; tk++) {
    int n = n0 + t0 + tk;
    if (n < SEQ) {
      float di = 1.0f / den[tk];
      bf16x8 o;
#pragma unroll
      for (int e = 0; e < 8; e++) o[e] = (bft)(acc[tk][e] * di);
      *(bf16x8*)(ATTN + ((size_t)(b * SEQ + n)) * DMODEL + h * 64 + e0) = o;
    }
  }
}

// ---------------- K5: out GEMM (M=32800, N=768, K=768) + bias, fp32 out ----------------
__global__ __launch_bounds__(256) void k_out_gemm(
    const bft* __restrict__ A, const bft* __restrict__ W,
    const float* __restrict__ BIAS, float* __restrict__ OUT) {
  __shared__ __align__(16) bft sA[128 * 64];
  __shared__ __align__(16) bft sB[128 * 64];
  const int tid = threadIdx.x;
  const int lane = tid & 63;
  const int lm = lane & 15;
  const int quad = lane >> 4;
  const int wid = tid >> 6;
  const int wm = (wid & 1) << 6;
  const int wn = (wid >> 1) << 6;
  const int m0 = blockIdx.x * 128;
  const int n0 = blockIdx.y * 128;
  const int sw = lm & 7;
  const int o0 = (quad ^ sw) << 3;
  const int o1 = ((4 + quad) ^ sw) << 3;

  f32x4 acc[4][4] = {};

  for (int kt = 0; kt < DMODEL; kt += 64) {
#pragma unroll
    for (int it = 0; it < 4; it++) {
      int c = it * 256 + tid;
      int row = c >> 3;
      int col = ((c & 7) ^ (row & 7)) << 3;
      int ar = m0 + row;
      if (ar >= MROWS) ar = MROWS - 1;
      gl_lds16(A + (size_t)ar * DMODEL + kt + col, sA + c * 8);
      gl_lds16(W + (size_t)(n0 + row) * DMODEL + kt + col, sB + c * 8);
    }
    __syncthreads();
#pragma unroll
    for (int kk = 0; kk < 2; kk++) {
      const int off = kk ? o1 : o0;
      bf16x8 af[4], bb[4];
#pragma unroll
      for (int i = 0; i < 4; i++)
        af[i] = *(const bf16x8*)(sA + (wm + i * 16 + lm) * 64 + off);
#pragma unroll
      for (int j = 0; j < 4; j++)
        bb[j] = *(const bf16x8*)(sB + (wn + j * 16 + lm) * 64 + off);
#pragma unroll
      for (int i = 0; i < 4; i++)
#pragma unroll
        for (int j = 0; j < 4; j++)
          acc[i][j] = __builtin_amdgcn_mfma_f32_16x16x32_bf16(af[i], bb[j], acc[i][j], 0, 0, 0);
    }
    __syncthreads();
  }

#pragma unroll
  for (int i = 0; i < 4; i++) {
#pragma unroll
    for (int r = 0; r < 4; r++) {
      int m = m0 + wm + i * 16 + quad * 4 + r;
      if (m < MROWS) {
#pragma unroll
        for (int j = 0; j < 4; j++) {
          int g = n0 + wn + j * 16 + lm;
          OUT[(size_t)m * DMODEL + g] = acc[i][j][r] + BIAS[g];
        }
      }
    }
  }
}

extern "C" void kernel_launch(void* const* d_in, const int* in_sizes, int n_in,
                              void* d_out, int out_size, void* d_ws, size_t ws_size,
                              hipStream_t stream) {
  const float* x = (const float*)d_in[0];
  const float* wqkv = (const float*)d_in[1];
  const float* wout = (const float*)d_in[2];
  const float* bout = (const float*)d_in[3];
  const float* proj = (const float*)d_in[4];
  const float* fc = (const float*)d_in[5];
  const float* fs = (const float*)d_in[6];
  float* outp = (float*)d_out;

  // workspace layout (bytes, all 16B-aligned)
  char* ws = (char*)d_ws;
  const size_t xb_bytes = (size_t)MROWS * DMODEL * 2;               // 50,457,600
  const size_t qkv_bytes = (size_t)3 * BHN * SEQ * HD * 2;          // 151,142,400
  const size_t wqkvb_bytes = (size_t)3 * DMODEL * DMODEL * 2;       // 3,538,944
  const size_t woutb_bytes = (size_t)DMODEL * DMODEL * 2;           // 1,179,648
  const size_t projb_bytes = (size_t)HD * HD * 2;                   // 8,192
  const size_t ctx_bytes = (size_t)BHN * 64 * 64 * 4;               // 6,291,456
  const size_t ks_bytes = (size_t)BHN * 64 * 4;                     // 98,304

  bft* xb = (bft*)ws;  // dead after K1 -> reused as attn
  bft* qkvb = (bft*)(ws + xb_bytes);
  bft* wqkvb = (bft*)(ws + xb_bytes + qkv_bytes);
  bft* woutb = (bft*)(ws + xb_bytes + qkv_bytes + wqkvb_bytes);
  bft* projb = (bft*)(ws + xb_bytes + qkv_bytes + wqkvb_bytes + woutb_bytes);
  float* ctx = (float*)(ws + xb_bytes + qkv_bytes + wqkvb_bytes + woutb_bytes + projb_bytes);
  float* ksum = (float*)(ws + xb_bytes + qkv_bytes + wqkvb_bytes + woutb_bytes + projb_bytes + ctx_bytes);
  bft* attn = xb;

  bft* qreg = qkvb;  // holds qf after fused K1
  bft* kreg = qkvb + (size_t)BHN * SEQ * HD;  // kf
  bft* vreg = qkvb + (size_t)2 * BHN * SEQ * HD;  // v

  dim3 blk(256);
  // casts
  k_cast<<<dim3((MROWS * DMODEL / 4 + 255) / 256), blk, 0, stream>>>(x, xb, MROWS * DMODEL / 4);
  k_cast<<<dim3((3 * DMODEL * DMODEL / 4 + 255) / 256), blk, 0, stream>>>(wqkv, wqkvb, 3 * DMODEL * DMODEL / 4);
  k_cast<<<dim3((DMODEL * DMODEL / 4 + 255) / 256), blk, 0, stream>>>(wout, woutb, DMODEL * DMODEL / 4);
  k_cast<<<dim3((HD * HD / 4 + 255) / 256), blk, 0, stream>>>(proj, projb, HD * HD / 4);

  // zero ctx + ksum (adjacent) for atomic accumulation
  hipMemsetAsync(ctx, 0, ctx_bytes + ks_bytes, stream);

  k_qkv_gemm<<<dim3(257, 18), blk, 0, stream>>>(xb, wqkvb, projb, fc, fs, qkvb);
  k_context<<<dim3(BHN, CSPLIT), blk, 0, stream>>>(kreg, vreg, ctx, ksum);
  k_qside<<<dim3(BHN, 9), blk, 0, stream>>>(qreg, ctx, ksum, attn);
  k_out_gemm<<<dim3(257, 6), blk, 0, stream>>>(attn, woutb, bout, outp);
  (void)in_sizes; (void)n_in; (void)out_size; (void)ws_size;
}

// Round 3
// 586.330 us; speedup vs baseline: 1.2752x; 1.2475x over previous
//
#include <hip/hip_runtime.h>
#include <stdint.h>
#include <stddef.h>

typedef __bf16 bft;
typedef __bf16 bf16x4 __attribute__((ext_vector_type(4)));
typedef __bf16 bf16x8 __attribute__((ext_vector_type(8)));
typedef float f32x4 __attribute__((ext_vector_type(4)));

#define NH 12
#define HD 64
#define SEQ 1025
#define NB 32
#define DMODEL 768
#define MROWS (NB * SEQ)   /* 32800 */
#define BHN (NB * NH)      /* 384 */
#define BSTR 1040          /* padded per-batch token stride for QKV GEMM M dim */
#define MP (NB * BSTR)     /* 33280 padded M */
#define SEQP 1056          /* kfT/vT column stride (33 chunks of 32) */

__device__ __forceinline__ void gl_lds16(const void* g, void* l) {
  __builtin_amdgcn_global_load_lds(
      (const __attribute__((address_space(1))) void*)g,
      (__attribute__((address_space(3))) void*)l, 16, 0, 0);
}

__device__ __forceinline__ bf16x4 ds_tr16(const bft* p, int boff) {
  bf16x4 d;
  asm volatile("ds_read_b64_tr_b16 %0, %1 offset:%2"
               : "=v"(d)
               : "v"((const __attribute__((address_space(3))) bft*)p), "i"(boff)
               : "memory");
  return d;
}

__device__ __forceinline__ void lgkm0() {
  asm volatile("s_waitcnt lgkmcnt(0)" ::: "memory");
}

// ---------------- K0: fp32 -> bf16 cast ----------------
__global__ __launch_bounds__(256) void k_cast(
    const float* __restrict__ S, bft* __restrict__ D, int n4) {
  int i = blockIdx.x * 256 + threadIdx.x;
  if (i < n4) {
    f32x4 v = *(const f32x4*)(S + (size_t)i * 4);
    bf16x4 o;
    o[0] = (bft)v[0]; o[1] = (bft)v[1]; o[2] = (bft)v[2]; o[3] = (bft)v[3];
    *(bf16x4*)(D + (size_t)i * 4) = o;
  }
}

// zero pad columns [1025,1056) of kfT/vT rows
__global__ __launch_bounds__(256) void k_padzero(bft* __restrict__ KFT, bft* __restrict__ VT) {
  int r = blockIdx.x * 256 + threadIdx.x;
  if (r < BHN * 64) {
    bft* a = KFT + (size_t)r * SEQP + 1025;
    bft* b = VT + (size_t)r * SEQP + 1025;
#pragma unroll
    for (int i = 0; i < 31; ++i) { a[i] = (bft)0.f; b[i] = (bft)0.f; }
  }
}

// ---------------- K1: QKV GEMM + fused RoPE + feature map ----------------
// grid (260, 18). y/6 = s (0=q,1=k,2=v). M padded: m = b*1040 + n.
__global__ __launch_bounds__(256) void k_qkv_gemm(
    const bft* __restrict__ X, const bft* __restrict__ W,
    const bft* __restrict__ P,
    const float* __restrict__ FC, const float* __restrict__ FS,
    bft* __restrict__ QF, bft* __restrict__ KFT, bft* __restrict__ VT) {
  __shared__ __align__(16) bft sA[128 * 64];
  __shared__ __align__(16) bft sB[128 * 64];
  __shared__ __align__(16) bft sP[64 * 64];
  const int tid = threadIdx.x;
  const int lane = tid & 63;
  const int lm = lane & 15;
  const int quad = lane >> 4;
  const int wid = tid >> 6;
  const int wm = (wid & 1) << 6;
  const int wn = (wid >> 1) << 6;
  const int m0 = blockIdx.x * 128;
  const int n0 = blockIdx.y * 128;
  const int sw = lm & 7;
  const int o0 = (quad ^ sw) << 3;
  const int o1 = ((4 + quad) ^ sw) << 3;

#pragma unroll
  for (int it = 0; it < 2; it++) {
    int c = it * 256 + tid;
    int row = c >> 3;
    int col = ((c & 7) ^ (row & 7)) << 3;
    gl_lds16(P + row * 64 + col, sP + c * 8);
  }

  f32x4 acc[4][4] = {};

  for (int kt = 0; kt < DMODEL; kt += 64) {
#pragma unroll
    for (int it = 0; it < 4; it++) {
      int c = it * 256 + tid;
      int row = c >> 3;
      int col = ((c & 7) ^ (row & 7)) << 3;
      int ar = m0 + row;
      int b2 = ar / BSTR;
      int nn = ar - b2 * BSTR;
      if (nn > 1024) nn = 1024;
      gl_lds16(X + (size_t)(b2 * SEQ + nn) * DMODEL + kt + col, sA + c * 8);
      gl_lds16(W + (size_t)(n0 + row) * DMODEL + kt + col, sB + c * 8);
    }
    __syncthreads();
#pragma unroll
    for (int kk = 0; kk < 2; kk++) {
      const int off = kk ? o1 : o0;
      bf16x8 af[4], bb[4];
#pragma unroll
      for (int i = 0; i < 4; i++)
        af[i] = *(const bf16x8*)(sA + (wm + i * 16 + lm) * 64 + off);
#pragma unroll
      for (int j = 0; j < 4; j++)
        bb[j] = *(const bf16x8*)(sB + (wn + j * 16 + lm) * 64 + off);
#pragma unroll
      for (int i = 0; i < 4; i++)
#pragma unroll
        for (int j = 0; j < 4; j++)
          acc[i][j] = __builtin_amdgcn_mfma_f32_16x16x32_bf16(af[i], bb[j], acc[i][j], 0, 0, 0);
    }
    __syncthreads();
  }

  const int s = blockIdx.y / 6;
  const int h = ((n0 + wn) - s * DMODEL) >> 6;

  bft* tt = sA + wid * 1024;
  const bft* tl = tt + quad * 128 + lm * 4;

  if (s < 2) {
#pragma unroll
    for (int i = 0; i < 4; i++) {
      const int tbase = m0 + wm + i * 16;     // mult of 16, whole tile in one batch
      const int bb2 = tbase / BSTR;
      const int nb = tbase - bb2 * BSTR;
      // RoPE in C-fragment layout on fp32 acc (single rounding)
#pragma unroll
      for (int j = 0; j < 4; j++) {
        const int d = j * 16 + lm;
        const int fj = d >> 1;
        bf16x4 w;
#pragma unroll
        for (int r = 0; r < 4; r++) {
          float v = acc[i][j][r];
          float pv = __shfl_xor(v, 1);
          int n = nb + quad * 4 + r;
          float ov = v;
          if (n >= 1) {
            int nc = (n <= 1024) ? n : 1024;  // clamp pad tokens (masked later)
            float cc = FC[(nc - 1) * 32 + fj];
            float ss = FS[(nc - 1) * 32 + fj];
            ov = (d & 1) ? (pv * ss + v * cc) : (v * cc - pv * ss);
          }
          w[r] = (bft)ov;
        }
        *(bf16x4*)(tt + d * 16 + quad * 4) = w;
      }
      lgkm0();
      bf16x4 i0a = ds_tr16(tl, 0);
      bf16x4 i0b = ds_tr16(tl, 128);
      bf16x4 i1a = ds_tr16(tl, 1024);
      bf16x4 i1b = ds_tr16(tl, 1152);
      lgkm0();
      __builtin_amdgcn_sched_barrier(0);
      bf16x8 af0, af1;
#pragma unroll
      for (int e = 0; e < 4; e++) {
        af0[e] = i0a[e]; af0[e + 4] = i0b[e];
        af1[e] = i1a[e]; af1[e + 4] = i1b[e];
      }

      if (s == 0) {
        // q: swapped MFMA -> D[feat][tok], token-per-lane, store [tok][feat]
        const int n = nb + lm;
        const bool valid = (n < SEQ);
        bft* dst = QF + ((size_t)(bb2 * NH + h) * SEQ + n) * HD;
#pragma unroll
        for (int j2 = 0; j2 < 4; j2++) {
          bf16x8 p0 = *(const bf16x8*)(sP + (j2 * 16 + lm) * 64 + o0);
          bf16x8 p1 = *(const bf16x8*)(sP + (j2 * 16 + lm) * 64 + o1);
          f32x4 fa = {0.f, 0.f, 0.f, 0.f};
          fa = __builtin_amdgcn_mfma_f32_16x16x32_bf16(p0, af0, fa, 0, 0, 0);
          fa = __builtin_amdgcn_mfma_f32_16x16x32_bf16(p1, af1, fa, 0, 0, 0);
          bf16x4 o;
#pragma unroll
          for (int r = 0; r < 4; r++) {
            float v = fa[r] * 0.35355339f;
            o[r] = (bft)(fmaxf(v, 0.f) + 1e-6f);
          }
          if (valid) *(bf16x4*)(dst + j2 * 16 + quad * 4) = o;
        }
      } else {
        // k: unswapped MFMA -> D[tok][feat], 4 consecutive tokens per lane,
        // store transposed kfT[f][n] with b64 (nq is 4-aligned)
        const int nq = nb + quad * 4;
#pragma unroll
        for (int j2 = 0; j2 < 4; j2++) {
          bf16x8 p0 = *(const bf16x8*)(sP + (j2 * 16 + lm) * 64 + o0);
          bf16x8 p1 = *(const bf16x8*)(sP + (j2 * 16 + lm) * 64 + o1);
          f32x4 fa = {0.f, 0.f, 0.f, 0.f};
          fa = __builtin_amdgcn_mfma_f32_16x16x32_bf16(af0, p0, fa, 0, 0, 0);
          fa = __builtin_amdgcn_mfma_f32_16x16x32_bf16(af1, p1, fa, 0, 0, 0);
          bf16x4 o;
#pragma unroll
          for (int r = 0; r < 4; r++) {
            float v = fa[r] * 0.35355339f;
            o[r] = (bft)(fmaxf(v, 0.f) + 1e-6f);
          }
          bft* rowp = KFT + ((size_t)(bb2 * NH + h) * 64 + j2 * 16 + lm) * SEQP;
          if (nq + 3 <= 1024) {
            *(bf16x4*)(rowp + nq) = o;
          } else {
#pragma unroll
            for (int r = 0; r < 4; r++)
              if (nq + r <= 1024) rowp[nq + r] = o[r];
          }
        }
      }
    }
  } else {
    // v: direct from acc -> vT[e][n], b64 stores (4 consecutive tokens/lane)
#pragma unroll
    for (int i = 0; i < 4; i++) {
      const int tbase = m0 + wm + i * 16;
      const int bb2 = tbase / BSTR;
      const int nb = tbase - bb2 * BSTR;
      const int nq = nb + quad * 4;
#pragma unroll
      for (int j = 0; j < 4; j++) {
        bf16x4 o;
#pragma unroll
        for (int r = 0; r < 4; r++) o[r] = (bft)acc[i][j][r];
        bft* rowp = VT + ((size_t)(bb2 * NH + h) * 64 + j * 16 + lm) * SEQP;
        if (nq + 3 <= 1024) {
          *(bf16x4*)(rowp + nq) = o;
        } else {
#pragma unroll
          for (int r = 0; r < 4; r++)
            if (nq + r <= 1024) rowp[nq + r] = o[r];
        }
      }
    }
  }
}

// ---------------- K3: context += kf^T @ v via MFMA (seq-split, atomic), fused ksum ----------------
// grid (BHN, 4). kfT/vT: [bh][64][SEQP] transposed, pad cols zeroed.
__global__ __launch_bounds__(256) void k_context(
    const bft* __restrict__ KFT, const bft* __restrict__ VT,
    float* __restrict__ CTX, float* __restrict__ KSUM) {
  __shared__ __align__(16) bft sK[64 * 32];
  __shared__ __align__(16) bft sV[64 * 32];
  const int tid = threadIdx.x;
  const int lane = tid & 63;
  const int lm = lane & 15;
  const int quad = lane >> 4;
  const int wid = tid >> 6;
  const int bh = blockIdx.x;
  const int y = blockIdx.y;
  const int c0 = (33 * y) / 4;
  const int c1 = (33 * (y + 1)) / 4;
  const bft* kb = KFT + (size_t)bh * 64 * SEQP;
  const bft* vb = VT + (size_t)bh * 64 * SEQP;
  const int f0 = wid * 16;
  const int srow = tid >> 2;
  const int sch = (tid & 3) * 8;

  bf16x8 ones;
#pragma unroll
  for (int e = 0; e < 8; e++) ones[e] = (bft)1.0f;

  f32x4 acc[4] = {};
  f32x4 ak = {0.f, 0.f, 0.f, 0.f};

  for (int c = c0; c < c1; ++c) {
    const int t0 = c * 32;
    gl_lds16(kb + (size_t)srow * SEQP + t0 + sch, sK + tid * 8);
    gl_lds16(vb + (size_t)srow * SEQP + t0 + sch, sV + tid * 8);
    __syncthreads();
    bf16x8 a = *(const bf16x8*)(sK + (f0 + lm) * 32 + quad * 8);
    ak = __builtin_amdgcn_mfma_f32_16x16x32_bf16(a, ones, ak, 0, 0, 0);
#pragma unroll
    for (int j = 0; j < 4; j++) {
      bf16x8 b = *(const bf16x8*)(sV + (j * 16 + lm) * 32 + quad * 8);
      acc[j] = __builtin_amdgcn_mfma_f32_16x16x32_bf16(a, b, acc[j], 0, 0, 0);
    }
    __syncthreads();
  }

  float* cp = CTX + (size_t)bh * 4096;
#pragma unroll
  for (int j = 0; j < 4; j++)
#pragma unroll
    for (int r = 0; r < 4; r++)
      atomicAdd(&cp[(f0 + quad * 4 + r) * 64 + j * 16 + lm], acc[j][r]);
  if (lm == 0) {
#pragma unroll
    for (int r = 0; r < 4; r++)
      atomicAdd(&KSUM[bh * 64 + f0 + quad * 4 + r], ak[r]);
  }
}

// ---------------- K3b: split ctx/ksum into bf16 hi/lo, transposed+pre-swizzled ----------------
__global__ __launch_bounds__(256) void k_ctxprep(
    const float* __restrict__ CTX, const float* __restrict__ KSUM,
    bft* __restrict__ CTH, bft* __restrict__ CTL,
    bft* __restrict__ KTH, bft* __restrict__ KTL) {
  const int bh = blockIdx.x;
  const int tid = threadIdx.x;
  const int e = tid >> 2;
  const int g = tid & 3;
  const float* src = CTX + (size_t)bh * 4096 + e;
  bf16x8 h0, l0, h1, l1;
#pragma unroll
  for (int k = 0; k < 16; ++k) {
    float v = src[(g * 16 + k) * 64];
    bft hi = (bft)v;
    bft lo = (bft)(v - (float)hi);
    if (k < 8) { h0[k] = hi; l0[k] = lo; }
    else       { h1[k - 8] = hi; l1[k - 8] = lo; }
  }
  const int c0 = (2 * g) ^ (e & 7);
  const int c1 = (2 * g + 1) ^ (e & 7);
  bft* dh = CTH + (size_t)bh * 4096 + e * 64;
  bft* dl = CTL + (size_t)bh * 4096 + e * 64;
  *(bf16x8*)(dh + c0 * 8) = h0;
  *(bf16x8*)(dh + c1 * 8) = h1;
  *(bf16x8*)(dl + c0 * 8) = l0;
  *(bf16x8*)(dl + c1 * 8) = l1;
  if (tid < 64) {
    float v = KSUM[bh * 64 + tid];
    bft hi = (bft)v;
    KTH[bh * 64 + tid] = hi;
    KTL[bh * 64 + tid] = (bft)(v - (float)hi);
  }
}

// ---------------- K4: attn = (qf @ ctx) * Dinv via MFMA (swapped: D[e][tok]) ----------------
// grid (BHN, 9). ctx as bf16 hi+lo (fp32-grade), den via 2-row ks MFMA + shfl.
__global__ __launch_bounds__(256) void k_qside(
    const bft* __restrict__ QF, const bft* __restrict__ CTH,
    const bft* __restrict__ CTL, const bft* __restrict__ KTH,
    const bft* __restrict__ KTL, bft* __restrict__ ATTN) {
  __shared__ __align__(16) bft sq[128 * 64];
  __shared__ __align__(16) bft sh[64 * 64];
  __shared__ __align__(16) bft sl[64 * 64];
  const int tid = threadIdx.x;
  const int lane = tid & 63;
  const int lm = lane & 15;
  const int quad = lane >> 4;
  const int wid = tid >> 6;
  const int bh = blockIdx.x;
  const int n0 = blockIdx.y * 128;
  const bft* qf = QF + ((size_t)bh * SEQ + n0) * HD;

#pragma unroll
  for (int it = 0; it < 4; it++) {
    int c = it * 256 + tid;
    int row = c >> 3;
    int col = ((c & 7) ^ (row & 7)) << 3;
    gl_lds16(qf + (size_t)row * 64 + col, sq + c * 8);
  }
#pragma unroll
  for (int it = 0; it < 2; it++) {
    int c = it * 256 + tid;
    gl_lds16(CTH + (size_t)bh * 4096 + c * 8, sh + c * 8);
    gl_lds16(CTL + (size_t)bh * 4096 + c * 8, sl + c * 8);
  }
  // ks fragments (A rows 0=hi,1=lo; others zero)
  bf16x8 kh0 = *(const bf16x8*)(KTH + bh * 64 + quad * 8);
  bf16x8 kh1 = *(const bf16x8*)(KTH + bh * 64 + 32 + quad * 8);
  bf16x8 kl0 = *(const bf16x8*)(KTL + bh * 64 + quad * 8);
  bf16x8 kl1 = *(const bf16x8*)(KTL + bh * 64 + 32 + quad * 8);
  bf16x8 zz = {};
  bf16x8 ad0 = (lm == 0) ? kh0 : (lm == 1) ? kl0 : zz;
  bf16x8 ad1 = (lm == 0) ? kh1 : (lm == 1) ? kl1 : zz;
  __syncthreads();

  // ctx A' fragments in registers: [eblk][kc], hi and lo
  bf16x8 ah[4][2], al[4][2];
#pragma unroll
  for (int eb = 0; eb < 4; eb++)
#pragma unroll
    for (int kc = 0; kc < 2; kc++) {
      const int off = ((quad + 4 * kc) ^ (lm & 7)) * 8;
      ah[eb][kc] = *(const bf16x8*)(sh + (eb * 16 + lm) * 64 + off);
      al[eb][kc] = *(const bf16x8*)(sl + (eb * 16 + lm) * 64 + off);
    }

  const int b = bh / NH;
  const int h = bh - b * NH;
#pragma unroll
  for (int tb2 = 0; tb2 < 2; tb2++) {
    const int tok0 = (wid * 2 + tb2) * 16;
    const int roff = (tok0 + lm) * 64;
    bf16x8 bq0 = *(const bf16x8*)(sq + roff + ((quad) ^ (lm & 7)) * 8);
    bf16x8 bq1 = *(const bf16x8*)(sq + roff + ((4 + quad) ^ (lm & 7)) * 8);
    f32x4 dacc = {0.f, 0.f, 0.f, 0.f};
    dacc = __builtin_amdgcn_mfma_f32_16x16x32_bf16(ad0, bq0, dacc, 0, 0, 0);
    dacc = __builtin_amdgcn_mfma_f32_16x16x32_bf16(ad1, bq1, dacc, 0, 0, 0);
    const float den = __shfl(dacc[0] + dacc[1], lm);
    const float dinv = 1.0f / den;
    f32x4 fa[4] = {};
#pragma unroll
    for (int eb = 0; eb < 4; eb++) {
      fa[eb] = __builtin_amdgcn_mfma_f32_16x16x32_bf16(ah[eb][0], bq0, fa[eb], 0, 0, 0);
      fa[eb] = __builtin_amdgcn_mfma_f32_16x16x32_bf16(al[eb][0], bq0, fa[eb], 0, 0, 0);
      fa[eb] = __builtin_amdgcn_mfma_f32_16x16x32_bf16(ah[eb][1], bq1, fa[eb], 0, 0, 0);
      fa[eb] = __builtin_amdgcn_mfma_f32_16x16x32_bf16(al[eb][1], bq1, fa[eb], 0, 0, 0);
    }
    const int n = n0 + tok0 + lm;
    if (n < SEQ) {
      bft* dst = ATTN + ((size_t)(b * SEQ + n)) * DMODEL + h * 64;
#pragma unroll
      for (int eb = 0; eb < 4; eb++) {
        bf16x4 o;
#pragma unroll
        for (int r = 0; r < 4; r++) o[r] = (bft)(fa[eb][r] * dinv);
        *(bf16x4*)(dst + eb * 16 + quad * 4) = o;
      }
    }
  }
}

// ---------------- K5: out GEMM (M=32800, N=768, K=768) + bias, fp32 out ----------------
__global__ __launch_bounds__(256) void k_out_gemm(
    const bft* __restrict__ A, const bft* __restrict__ W,
    const float* __restrict__ BIAS, float* __restrict__ OUT) {
  __shared__ __align__(16) bft sA[128 * 64];
  __shared__ __align__(16) bft sB[128 * 64];
  const int tid = threadIdx.x;
  const int lane = tid & 63;
  const int lm = lane & 15;
  const int quad = lane >> 4;
  const int wid = tid >> 6;
  const int wm = (wid & 1) << 6;
  const int wn = (wid >> 1) << 6;
  const int m0 = blockIdx.x * 128;
  const int n0 = blockIdx.y * 128;
  const int sw = lm & 7;
  const int o0 = (quad ^ sw) << 3;
  const int o1 = ((4 + quad) ^ sw) << 3;

  f32x4 acc[4][4] = {};

  for (int kt = 0; kt < DMODEL; kt += 64) {
#pragma unroll
    for (int it = 0; it < 4; it++) {
      int c = it * 256 + tid;
      int row = c >> 3;
      int col = ((c & 7) ^ (row & 7)) << 3;
      int ar = m0 + row;
      if (ar >= MROWS) ar = MROWS - 1;
      gl_lds16(A + (size_t)ar * DMODEL + kt + col, sA + c * 8);
      gl_lds16(W + (size_t)(n0 + row) * DMODEL + kt + col, sB + c * 8);
    }
    __syncthreads();
#pragma unroll
    for (int kk = 0; kk < 2; kk++) {
      const int off = kk ? o1 : o0;
      bf16x8 af[4], bb[4];
#pragma unroll
      for (int i = 0; i < 4; i++)
        af[i] = *(const bf16x8*)(sA + (wm + i * 16 + lm) * 64 + off);
#pragma unroll
      for (int j = 0; j < 4; j++)
        bb[j] = *(const bf16x8*)(sB + (wn + j * 16 + lm) * 64 + off);
#pragma unroll
      for (int i = 0; i < 4; i++)
#pragma unroll
        for (int j = 0; j < 4; j++)
          acc[i][j] = __builtin_amdgcn_mfma_f32_16x16x32_bf16(af[i], bb[j], acc[i][j], 0, 0, 0);
    }
    __syncthreads();
  }

#pragma unroll
  for (int i = 0; i < 4; i++) {
#pragma unroll
    for (int r = 0; r < 4; r++) {
      int m = m0 + wm + i * 16 + quad * 4 + r;
      if (m < MROWS) {
#pragma unroll
        for (int j = 0; j < 4; j++) {
          int g = n0 + wn + j * 16 + lm;
          OUT[(size_t)m * DMODEL + g] = acc[i][j][r] + BIAS[g];
        }
      }
    }
  }
}

extern "C" void kernel_launch(void* const* d_in, const int* in_sizes, int n_in,
                              void* d_out, int out_size, void* d_ws, size_t ws_size,
                              hipStream_t stream) {
  const float* x = (const float*)d_in[0];
  const float* wqkv = (const float*)d_in[1];
  const float* wout = (const float*)d_in[2];
  const float* bout = (const float*)d_in[3];
  const float* proj = (const float*)d_in[4];
  const float* fc = (const float*)d_in[5];
  const float* fs = (const float*)d_in[6];
  float* outp = (float*)d_out;

  char* ws = (char*)d_ws;
  const size_t xb_bytes = (size_t)MROWS * DMODEL * 2;        // 50,457,600
  const size_t qf_bytes = (size_t)BHN * SEQ * HD * 2;        // 50,380,800
  const size_t kt_bytes = (size_t)BHN * 64 * SEQP * 2;       // 51,904,512
  const size_t wqkvb_bytes = (size_t)3 * DMODEL * DMODEL * 2;
  const size_t woutb_bytes = (size_t)DMODEL * DMODEL * 2;
  const size_t ctx_bytes = (size_t)BHN * 64 * 64 * 4;        // 6,291,456
  const size_t ks_bytes = (size_t)BHN * 64 * 4;              // 98,304
  const size_t ctt_bytes = (size_t)BHN * 64 * 64 * 2;        // 3,145,728
  const size_t kst_bytes = (size_t)BHN * 64 * 2;             // 49,152

  bft* xb = (bft*)ws;                                  // X bf16; dead after k_qkv
  bft* qfb = (bft*)(ws + xb_bytes);
  bft* kft = (bft*)(ws + xb_bytes + qf_bytes);         // dead after k_context -> attn
  bft* vt = (bft*)(ws + xb_bytes + qf_bytes + kt_bytes);
  bft* wqkvb = (bft*)(ws + xb_bytes + qf_bytes + 2 * kt_bytes);
  bft* woutb = (bft*)(ws + xb_bytes + qf_bytes + 2 * kt_bytes + wqkvb_bytes);
  bft* projb = (bft*)(ws + xb_bytes + qf_bytes + 2 * kt_bytes + wqkvb_bytes + woutb_bytes);

  // aliases into xb region (live only after k_qkv)
  float* ctx = (float*)ws;
  float* ksum = (float*)(ws + ctx_bytes);
  bft* cth = (bft*)(ws + ctx_bytes + ks_bytes);
  bft* ctl = (bft*)(ws + ctx_bytes + ks_bytes + ctt_bytes);
  bft* kth = (bft*)(ws + ctx_bytes + ks_bytes + 2 * ctt_bytes);
  bft* ktl = (bft*)(ws + ctx_bytes + ks_bytes + 2 * ctt_bytes + kst_bytes);
  bft* attn = kft;  // alias kfT region (dead after k_context)

  dim3 blk(256);
  k_cast<<<dim3((MROWS * DMODEL / 4 + 255) / 256), blk, 0, stream>>>(x, xb, MROWS * DMODEL / 4);
  k_cast<<<dim3((3 * DMODEL * DMODEL / 4 + 255) / 256), blk, 0, stream>>>(wqkv, wqkvb, 3 * DMODEL * DMODEL / 4);
  k_cast<<<dim3((DMODEL * DMODEL / 4 + 255) / 256), blk, 0, stream>>>(wout, woutb, DMODEL * DMODEL / 4);
  k_cast<<<dim3((HD * HD / 4 + 255) / 256), blk, 0, stream>>>(proj, projb, HD * HD / 4);
  k_padzero<<<dim3((BHN * 64 + 255) / 256), blk, 0, stream>>>(kft, vt);

  k_qkv_gemm<<<dim3(MP / 128, 18), blk, 0, stream>>>(xb, wqkvb, projb, fc, fs, qfb, kft, vt);

  // ctx region aliases xb: zero only after k_qkv has consumed X
  hipMemsetAsync(ctx, 0, ctx_bytes + ks_bytes, stream);

  k_context<<<dim3(BHN, 4), blk, 0, stream>>>(kft, vt, ctx, ksum);
  k_ctxprep<<<dim3(BHN), blk, 0, stream>>>(ctx, ksum, cth, ctl, kth, ktl);
  k_qside<<<dim3(BHN, 9), blk, 0, stream>>>(qfb, cth, ctl, kth, ktl, attn);
  k_out_gemm<<<dim3(257, 6), blk, 0, stream>>>(attn, woutb, bout, outp);
  (void)in_sizes; (void)n_in; (void)out_size; (void)ws_size;
}

// Round 4
// 515.876 us; speedup vs baseline: 1.4494x; 1.1366x over previous
//
#include <hip/hip_runtime.h>
#include <stdint.h>
#include <stddef.h>

typedef __bf16 bft;
typedef __bf16 bf16x4 __attribute__((ext_vector_type(4)));
typedef __bf16 bf16x8 __attribute__((ext_vector_type(8)));
typedef float f32x4 __attribute__((ext_vector_type(4)));

#define NH 12
#define HD 64
#define SEQ 1025
#define NB 32
#define DMODEL 768
#define MROWS (NB * SEQ)   /* 32800 */
#define BHN (NB * NH)      /* 384 */
#define BSTR 1040          /* padded per-batch token stride for QKV GEMM M dim */
#define MP (NB * BSTR)     /* 33280 padded M */
#define SEQP 1056          /* kfT/vT column stride (33 chunks of 32) */

__device__ __forceinline__ void gl_lds16(const void* g, void* l) {
  __builtin_amdgcn_global_load_lds(
      (const __attribute__((address_space(1))) void*)g,
      (__attribute__((address_space(3))) void*)l, 16, 0, 0);
}

__device__ __forceinline__ bf16x4 ds_tr16(const bft* p, int boff) {
  bf16x4 d;
  asm volatile("ds_read_b64_tr_b16 %0, %1 offset:%2"
               : "=v"(d)
               : "v"((const __attribute__((address_space(3))) bft*)p), "i"(boff)
               : "memory");
  return d;
}

__device__ __forceinline__ void lgkm0() {
  asm volatile("s_waitcnt lgkmcnt(0)" ::: "memory");
}

// ---------------- K0: fp32 -> bf16 cast ----------------
__global__ __launch_bounds__(256) void k_cast(
    const float* __restrict__ S, bft* __restrict__ D, int n4) {
  int i = blockIdx.x * 256 + threadIdx.x;
  if (i < n4) {
    f32x4 v = *(const f32x4*)(S + (size_t)i * 4);
    bf16x4 o;
    o[0] = (bft)v[0]; o[1] = (bft)v[1]; o[2] = (bft)v[2]; o[3] = (bft)v[3];
    *(bf16x4*)(D + (size_t)i * 4) = o;
  }
}

// zero pad columns [1025,1056) of kfT/vT rows
__global__ __launch_bounds__(256) void k_padzero(bft* __restrict__ KFT, bft* __restrict__ VT) {
  int r = blockIdx.x * 256 + threadIdx.x;
  if (r < BHN * 64) {
    bft* a = KFT + (size_t)r * SEQP + 1025;
    bft* b = VT + (size_t)r * SEQP + 1025;
#pragma unroll
    for (int i = 0; i < 31; ++i) { a[i] = (bft)0.f; b[i] = (bft)0.f; }
  }
}

// padded RoPE tables: FCP/FSP[1040][32]; row 0 and rows >1024 are (1,0)
__global__ __launch_bounds__(256) void k_ropeprep(
    const float* __restrict__ FC, const float* __restrict__ FS,
    float* __restrict__ FCP, float* __restrict__ FSP) {
  int i = blockIdx.x * 256 + threadIdx.x;
  if (i < 1040 * 32) {
    int n = i >> 5;
    int fj = i & 31;
    float c = 1.f, s = 0.f;
    if (n >= 1 && n <= 1024) {
      c = FC[(n - 1) * 32 + fj];
      s = FS[(n - 1) * 32 + fj];
    }
    FCP[i] = c;
    FSP[i] = s;
  }
}

// ---------------- K1: QKV GEMM + fused RoPE + feature map ----------------
// 1D grid 4680 = 8 XCD chunks x 585. Logical order column-fastest (18 col-blocks
// share an A-tile consecutively; all 18 W-tiles (3.5MB) stay in one XCD's L2).
__global__ __launch_bounds__(256) void k_qkv_gemm(
    const bft* __restrict__ X, const bft* __restrict__ W,
    const bft* __restrict__ P,
    const float* __restrict__ FCP, const float* __restrict__ FSP,
    bft* __restrict__ QF, bft* __restrict__ KFT, bft* __restrict__ VT) {
  __shared__ __align__(16) bft sA[128 * 64];
  __shared__ __align__(16) bft sB[128 * 64];
  __shared__ __align__(16) bft sP[64 * 64];
  const int tid = threadIdx.x;
  const int lane = tid & 63;
  const int lm = lane & 15;
  const int quad = lane >> 4;
  const int wid = tid >> 6;
  const int wm = (wid & 1) << 6;
  const int wn = (wid >> 1) << 6;
  // XCD-chunked bijective swizzle: 4680 = 8 * 585
  const int lin = blockIdx.x;
  const int logical = (lin & 7) * 585 + (lin >> 3);
  const int cb = logical % 18;
  const int rb = logical / 18;
  const int m0 = rb * 128;
  const int n0 = cb * 128;
  const int sw = lm & 7;
  const int o0 = (quad ^ sw) << 3;
  const int o1 = ((4 + quad) ^ sw) << 3;

#pragma unroll
  for (int it = 0; it < 2; it++) {
    int c = it * 256 + tid;
    int row = c >> 3;
    int col = ((c & 7) ^ (row & 7)) << 3;
    gl_lds16(P + row * 64 + col, sP + c * 8);
  }

  // hoist K-invariant staging addresses
  const bft* aptr[4];
  const bft* bptr[4];
#pragma unroll
  for (int it = 0; it < 4; it++) {
    int c = it * 256 + tid;
    int row = c >> 3;
    int col = ((c & 7) ^ (row & 7)) << 3;
    int ar = m0 + row;
    int b2 = ar / BSTR;
    int nn = ar - b2 * BSTR;
    if (nn > 1024) nn = 1024;
    aptr[it] = X + (size_t)(b2 * SEQ + nn) * DMODEL + col;
    bptr[it] = W + (size_t)(n0 + row) * DMODEL + col;
  }

  f32x4 acc[4][4] = {};

  for (int kt = 0; kt < DMODEL; kt += 64) {
#pragma unroll
    for (int it = 0; it < 4; it++) {
      int c = it * 256 + tid;
      gl_lds16(aptr[it], sA + c * 8);
      gl_lds16(bptr[it], sB + c * 8);
      aptr[it] += 64;
      bptr[it] += 64;
    }
    __syncthreads();
#pragma unroll
    for (int kk = 0; kk < 2; kk++) {
      const int off = kk ? o1 : o0;
      bf16x8 af[4], bb[4];
#pragma unroll
      for (int i = 0; i < 4; i++)
        af[i] = *(const bf16x8*)(sA + (wm + i * 16 + lm) * 64 + off);
#pragma unroll
      for (int j = 0; j < 4; j++)
        bb[j] = *(const bf16x8*)(sB + (wn + j * 16 + lm) * 64 + off);
#pragma unroll
      for (int i = 0; i < 4; i++)
#pragma unroll
        for (int j = 0; j < 4; j++)
          acc[i][j] = __builtin_amdgcn_mfma_f32_16x16x32_bf16(af[i], bb[j], acc[i][j], 0, 0, 0);
    }
    __syncthreads();
  }

  const int s = cb / 6;
  const int h = ((n0 + wn) - s * DMODEL) >> 6;

  bft* tt = sA + wid * 1024;
  const bft* tl = tt + quad * 128 + lm * 4;

  if (s < 2) {
    const float sgn = (lm & 1) ? 1.f : -1.f;
#pragma unroll
    for (int i = 0; i < 4; i++) {
      const int tbase = m0 + wm + i * 16;     // mult of 16, whole tile in one batch
      const int bb2 = tbase / BSTR;
      const int nb = tbase - bb2 * BSTR;
      // RoPE in C-fragment layout on fp32 acc (single rounding), branchless via
      // padded tables (row 0 / pad rows = identity rotation)
#pragma unroll
      for (int j = 0; j < 4; j++) {
        const int fj = (j * 16 + lm) >> 1;
        const int d = j * 16 + lm;
        bf16x4 w;
#pragma unroll
        for (int r = 0; r < 4; r++) {
          float v = acc[i][j][r];
          float pv = __shfl_xor(v, 1);
          int n = nb + quad * 4 + r;          // < 1040, table-covered
          float cc = FCP[n * 32 + fj];
          float ss = FSP[n * 32 + fj];
          w[r] = (bft)fmaf(pv, sgn * ss, v * cc);
        }
        *(bf16x4*)(tt + d * 16 + quad * 4) = w;
      }
      lgkm0();
      bf16x4 i0a = ds_tr16(tl, 0);
      bf16x4 i0b = ds_tr16(tl, 128);
      bf16x4 i1a = ds_tr16(tl, 1024);
      bf16x4 i1b = ds_tr16(tl, 1152);
      lgkm0();
      __builtin_amdgcn_sched_barrier(0);
      bf16x8 af0, af1;
#pragma unroll
      for (int e = 0; e < 4; e++) {
        af0[e] = i0a[e]; af0[e + 4] = i0b[e];
        af1[e] = i1a[e]; af1[e + 4] = i1b[e];
      }

      if (s == 0) {
        // q: swapped MFMA -> D[feat][tok], token-per-lane, store [tok][feat]
        const int n = nb + lm;
        const bool valid = (n < SEQ);
        bft* dst = QF + ((size_t)(bb2 * NH + h) * SEQ + n) * HD;
#pragma unroll
        for (int j2 = 0; j2 < 4; j2++) {
          bf16x8 p0 = *(const bf16x8*)(sP + (j2 * 16 + lm) * 64 + o0);
          bf16x8 p1 = *(const bf16x8*)(sP + (j2 * 16 + lm) * 64 + o1);
          f32x4 fa = {0.f, 0.f, 0.f, 0.f};
          fa = __builtin_amdgcn_mfma_f32_16x16x32_bf16(p0, af0, fa, 0, 0, 0);
          fa = __builtin_amdgcn_mfma_f32_16x16x32_bf16(p1, af1, fa, 0, 0, 0);
          bf16x4 o;
#pragma unroll
          for (int r = 0; r < 4; r++) {
            float v = fa[r] * 0.35355339f;
            o[r] = (bft)(fmaxf(v, 0.f) + 1e-6f);
          }
          if (valid) *(bf16x4*)(dst + j2 * 16 + quad * 4) = o;
        }
      } else {
        // k: unswapped MFMA -> D[tok][feat], store transposed kfT[f][n], b64
        const int nq = nb + quad * 4;
#pragma unroll
        for (int j2 = 0; j2 < 4; j2++) {
          bf16x8 p0 = *(const bf16x8*)(sP + (j2 * 16 + lm) * 64 + o0);
          bf16x8 p1 = *(const bf16x8*)(sP + (j2 * 16 + lm) * 64 + o1);
          f32x4 fa = {0.f, 0.f, 0.f, 0.f};
          fa = __builtin_amdgcn_mfma_f32_16x16x32_bf16(af0, p0, fa, 0, 0, 0);
          fa = __builtin_amdgcn_mfma_f32_16x16x32_bf16(af1, p1, fa, 0, 0, 0);
          bf16x4 o;
#pragma unroll
          for (int r = 0; r < 4; r++) {
            float v = fa[r] * 0.35355339f;
            o[r] = (bft)(fmaxf(v, 0.f) + 1e-6f);
          }
          bft* rowp = KFT + ((size_t)(bb2 * NH + h) * 64 + j2 * 16 + lm) * SEQP;
          if (nq + 3 <= 1024) {
            *(bf16x4*)(rowp + nq) = o;
          } else {
#pragma unroll
            for (int r = 0; r < 4; r++)
              if (nq + r <= 1024) rowp[nq + r] = o[r];
          }
        }
      }
    }
  } else {
    // v: direct from acc -> vT[e][n], b64 stores
#pragma unroll
    for (int i = 0; i < 4; i++) {
      const int tbase = m0 + wm + i * 16;
      const int bb2 = tbase / BSTR;
      const int nb = tbase - bb2 * BSTR;
      const int nq = nb + quad * 4;
#pragma unroll
      for (int j = 0; j < 4; j++) {
        bf16x4 o;
#pragma unroll
        for (int r = 0; r < 4; r++) o[r] = (bft)acc[i][j][r];
        bft* rowp = VT + ((size_t)(bb2 * NH + h) * 64 + j * 16 + lm) * SEQP;
        if (nq + 3 <= 1024) {
          *(bf16x4*)(rowp + nq) = o;
        } else {
#pragma unroll
          for (int r = 0; r < 4; r++)
            if (nq + r <= 1024) rowp[nq + r] = o[r];
        }
      }
    }
  }
}

// ---------------- K3: context += kf^T @ v via MFMA (seq-split, atomic), fused ksum ----------------
__global__ __launch_bounds__(256) void k_context(
    const bft* __restrict__ KFT, const bft* __restrict__ VT,
    float* __restrict__ CTX, float* __restrict__ KSUM) {
  __shared__ __align__(16) bft sK[64 * 32];
  __shared__ __align__(16) bft sV[64 * 32];
  const int tid = threadIdx.x;
  const int lane = tid & 63;
  const int lm = lane & 15;
  const int quad = lane >> 4;
  const int wid = tid >> 6;
  const int bh = blockIdx.x;
  const int y = blockIdx.y;
  const int c0 = (33 * y) / 4;
  const int c1 = (33 * (y + 1)) / 4;
  const bft* kb = KFT + (size_t)bh * 64 * SEQP;
  const bft* vb = VT + (size_t)bh * 64 * SEQP;
  const int f0 = wid * 16;
  const int srow = tid >> 2;
  const int sch = (tid & 3) * 8;

  bf16x8 ones;
#pragma unroll
  for (int e = 0; e < 8; e++) ones[e] = (bft)1.0f;

  f32x4 acc[4] = {};
  f32x4 ak = {0.f, 0.f, 0.f, 0.f};

  for (int c = c0; c < c1; ++c) {
    const int t0 = c * 32;
    gl_lds16(kb + (size_t)srow * SEQP + t0 + sch, sK + tid * 8);
    gl_lds16(vb + (size_t)srow * SEQP + t0 + sch, sV + tid * 8);
    __syncthreads();
    bf16x8 a = *(const bf16x8*)(sK + (f0 + lm) * 32 + quad * 8);
    ak = __builtin_amdgcn_mfma_f32_16x16x32_bf16(a, ones, ak, 0, 0, 0);
#pragma unroll
    for (int j = 0; j < 4; j++) {
      bf16x8 b = *(const bf16x8*)(sV + (j * 16 + lm) * 32 + quad * 8);
      acc[j] = __builtin_amdgcn_mfma_f32_16x16x32_bf16(a, b, acc[j], 0, 0, 0);
    }
    __syncthreads();
  }

  float* cp = CTX + (size_t)bh * 4096;
#pragma unroll
  for (int j = 0; j < 4; j++)
#pragma unroll
    for (int r = 0; r < 4; r++)
      atomicAdd(&cp[(f0 + quad * 4 + r) * 64 + j * 16 + lm], acc[j][r]);
  if (lm == 0) {
#pragma unroll
    for (int r = 0; r < 4; r++)
      atomicAdd(&KSUM[bh * 64 + f0 + quad * 4 + r], ak[r]);
  }
}

// ---------------- K3b: split ctx/ksum into bf16 hi/lo, transposed+pre-swizzled ----------------
__global__ __launch_bounds__(256) void k_ctxprep(
    const float* __restrict__ CTX, const float* __restrict__ KSUM,
    bft* __restrict__ CTH, bft* __restrict__ CTL,
    bft* __restrict__ KTH, bft* __restrict__ KTL) {
  const int bh = blockIdx.x;
  const int tid = threadIdx.x;
  const int e = tid >> 2;
  const int g = tid & 3;
  const float* src = CTX + (size_t)bh * 4096 + e;
  bf16x8 h0, l0, h1, l1;
#pragma unroll
  for (int k = 0; k < 16; ++k) {
    float v = src[(g * 16 + k) * 64];
    bft hi = (bft)v;
    bft lo = (bft)(v - (float)hi);
    if (k < 8) { h0[k] = hi; l0[k] = lo; }
    else       { h1[k - 8] = hi; l1[k - 8] = lo; }
  }
  const int c0 = (2 * g) ^ (e & 7);
  const int c1 = (2 * g + 1) ^ (e & 7);
  bft* dh = CTH + (size_t)bh * 4096 + e * 64;
  bft* dl = CTL + (size_t)bh * 4096 + e * 64;
  *(bf16x8*)(dh + c0 * 8) = h0;
  *(bf16x8*)(dh + c1 * 8) = h1;
  *(bf16x8*)(dl + c0 * 8) = l0;
  *(bf16x8*)(dl + c1 * 8) = l1;
  if (tid < 64) {
    float v = KSUM[bh * 64 + tid];
    bft hi = (bft)v;
    KTH[bh * 64 + tid] = hi;
    KTL[bh * 64 + tid] = (bft)(v - (float)hi);
  }
}

// ---------------- K4: attn = (qf @ ctx) * Dinv via MFMA (swapped: D[e][tok]) ----------------
__global__ __launch_bounds__(256) void k_qside(
    const bft* __restrict__ QF, const bft* __restrict__ CTH,
    const bft* __restrict__ CTL, const bft* __restrict__ KTH,
    const bft* __restrict__ KTL, bft* __restrict__ ATTN) {
  __shared__ __align__(16) bft sq[128 * 64];
  __shared__ __align__(16) bft sh[64 * 64];
  __shared__ __align__(16) bft sl[64 * 64];
  const int tid = threadIdx.x;
  const int lane = tid & 63;
  const int lm = lane & 15;
  const int quad = lane >> 4;
  const int wid = tid >> 6;
  const int bh = blockIdx.x;
  const int n0 = blockIdx.y * 128;
  const bft* qf = QF + ((size_t)bh * SEQ + n0) * HD;

#pragma unroll
  for (int it = 0; it < 4; it++) {
    int c = it * 256 + tid;
    int row = c >> 3;
    int col = ((c & 7) ^ (row & 7)) << 3;
    gl_lds16(qf + (size_t)row * 64 + col, sq + c * 8);
  }
#pragma unroll
  for (int it = 0; it < 2; it++) {
    int c = it * 256 + tid;
    gl_lds16(CTH + (size_t)bh * 4096 + c * 8, sh + c * 8);
    gl_lds16(CTL + (size_t)bh * 4096 + c * 8, sl + c * 8);
  }
  bf16x8 kh0 = *(const bf16x8*)(KTH + bh * 64 + quad * 8);
  bf16x8 kh1 = *(const bf16x8*)(KTH + bh * 64 + 32 + quad * 8);
  bf16x8 kl0 = *(const bf16x8*)(KTL + bh * 64 + quad * 8);
  bf16x8 kl1 = *(const bf16x8*)(KTL + bh * 64 + 32 + quad * 8);
  bf16x8 zz = {};
  bf16x8 ad0 = (lm == 0) ? kh0 : (lm == 1) ? kl0 : zz;
  bf16x8 ad1 = (lm == 0) ? kh1 : (lm == 1) ? kl1 : zz;
  __syncthreads();

  bf16x8 ah[4][2], al[4][2];
#pragma unroll
  for (int eb = 0; eb < 4; eb++)
#pragma unroll
    for (int kc = 0; kc < 2; kc++) {
      const int off = ((quad + 4 * kc) ^ (lm & 7)) * 8;
      ah[eb][kc] = *(const bf16x8*)(sh + (eb * 16 + lm) * 64 + off);
      al[eb][kc] = *(const bf16x8*)(sl + (eb * 16 + lm) * 64 + off);
    }

  const int b = bh / NH;
  const int h = bh - b * NH;
#pragma unroll
  for (int tb2 = 0; tb2 < 2; tb2++) {
    const int tok0 = (wid * 2 + tb2) * 16;
    const int roff = (tok0 + lm) * 64;
    bf16x8 bq0 = *(const bf16x8*)(sq + roff + ((quad) ^ (lm & 7)) * 8);
    bf16x8 bq1 = *(const bf16x8*)(sq + roff + ((4 + quad) ^ (lm & 7)) * 8);
    f32x4 dacc = {0.f, 0.f, 0.f, 0.f};
    dacc = __builtin_amdgcn_mfma_f32_16x16x32_bf16(ad0, bq0, dacc, 0, 0, 0);
    dacc = __builtin_amdgcn_mfma_f32_16x16x32_bf16(ad1, bq1, dacc, 0, 0, 0);
    const float den = __shfl(dacc[0] + dacc[1], lm);
    const float dinv = 1.0f / den;
    f32x4 fa[4] = {};
#pragma unroll
    for (int eb = 0; eb < 4; eb++) {
      fa[eb] = __builtin_amdgcn_mfma_f32_16x16x32_bf16(ah[eb][0], bq0, fa[eb], 0, 0, 0);
      fa[eb] = __builtin_amdgcn_mfma_f32_16x16x32_bf16(al[eb][0], bq0, fa[eb], 0, 0, 0);
      fa[eb] = __builtin_amdgcn_mfma_f32_16x16x32_bf16(ah[eb][1], bq1, fa[eb], 0, 0, 0);
      fa[eb] = __builtin_amdgcn_mfma_f32_16x16x32_bf16(al[eb][1], bq1, fa[eb], 0, 0, 0);
    }
    const int n = n0 + tok0 + lm;
    if (n < SEQ) {
      bft* dst = ATTN + ((size_t)(b * SEQ + n)) * DMODEL + h * 64;
#pragma unroll
      for (int eb = 0; eb < 4; eb++) {
        bf16x4 o;
#pragma unroll
        for (int r = 0; r < 4; r++) o[r] = (bft)(fa[eb][r] * dinv);
        *(bf16x4*)(dst + eb * 16 + quad * 4) = o;
      }
    }
  }
}

// ---------------- K5: out GEMM (M=32800, N=768, K=768) + bias, fp32 out ----------------
// 1D grid 1542, XCD-chunked bijective swizzle (q=192, r=6), column-fastest.
// Swapped MFMA -> D[g][m]: lane holds 4 consecutive g -> f32x4 stores.
__global__ __launch_bounds__(256) void k_out_gemm(
    const bft* __restrict__ A, const bft* __restrict__ W,
    const float* __restrict__ BIAS, float* __restrict__ OUT) {
  __shared__ __align__(16) bft sA[128 * 64];
  __shared__ __align__(16) bft sB[128 * 64];
  const int tid = threadIdx.x;
  const int lane = tid & 63;
  const int lm = lane & 15;
  const int quad = lane >> 4;
  const int wid = tid >> 6;
  const int wm = (wid & 1) << 6;
  const int wn = (wid >> 1) << 6;
  const int lin = blockIdx.x;
  const int xcd = lin & 7;
  const int slot = lin >> 3;
  const int base = (xcd < 6) ? xcd * 193 : 6 * 193 + (xcd - 6) * 192;
  const int logical = base + slot;
  const int cb = logical % 6;
  const int rb = logical / 6;
  const int m0 = rb * 128;
  const int n0 = cb * 128;
  const int sw = lm & 7;
  const int o0 = (quad ^ sw) << 3;
  const int o1 = ((4 + quad) ^ sw) << 3;

  const bft* aptr[4];
  const bft* bptr[4];
#pragma unroll
  for (int it = 0; it < 4; it++) {
    int c = it * 256 + tid;
    int row = c >> 3;
    int col = ((c & 7) ^ (row & 7)) << 3;
    int ar = m0 + row;
    if (ar >= MROWS) ar = MROWS - 1;
    aptr[it] = A + (size_t)ar * DMODEL + col;
    bptr[it] = W + (size_t)(n0 + row) * DMODEL + col;
  }

  f32x4 acc[4][4] = {};

  for (int kt = 0; kt < DMODEL; kt += 64) {
#pragma unroll
    for (int it = 0; it < 4; it++) {
      int c = it * 256 + tid;
      gl_lds16(aptr[it], sA + c * 8);
      gl_lds16(bptr[it], sB + c * 8);
      aptr[it] += 64;
      bptr[it] += 64;
    }
    __syncthreads();
#pragma unroll
    for (int kk = 0; kk < 2; kk++) {
      const int off = kk ? o1 : o0;
      bf16x8 af[4], bb[4];
#pragma unroll
      for (int i = 0; i < 4; i++)
        af[i] = *(const bf16x8*)(sA + (wm + i * 16 + lm) * 64 + off);
#pragma unroll
      for (int j = 0; j < 4; j++)
        bb[j] = *(const bf16x8*)(sB + (wn + j * 16 + lm) * 64 + off);
      // swapped: D rows = g (from bb), cols = m (from af)
#pragma unroll
      for (int i = 0; i < 4; i++)
#pragma unroll
        for (int j = 0; j < 4; j++)
          acc[i][j] = __builtin_amdgcn_mfma_f32_16x16x32_bf16(bb[j], af[i], acc[i][j], 0, 0, 0);
    }
    __syncthreads();
  }

#pragma unroll
  for (int i = 0; i < 4; i++) {
    const int m = m0 + wm + i * 16 + lm;
    if (m < MROWS) {
#pragma unroll
      for (int j = 0; j < 4; j++) {
        const int g = n0 + wn + j * 16 + quad * 4;
        f32x4 bias = *(const f32x4*)(BIAS + g);
        f32x4 o;
#pragma unroll
        for (int r = 0; r < 4; r++) o[r] = acc[i][j][r] + bias[r];
        *(f32x4*)(OUT + (size_t)m * DMODEL + g) = o;
      }
    }
  }
}

extern "C" void kernel_launch(void* const* d_in, const int* in_sizes, int n_in,
                              void* d_out, int out_size, void* d_ws, size_t ws_size,
                              hipStream_t stream) {
  const float* x = (const float*)d_in[0];
  const float* wqkv = (const float*)d_in[1];
  const float* wout = (const float*)d_in[2];
  const float* bout = (const float*)d_in[3];
  const float* proj = (const float*)d_in[4];
  const float* fc = (const float*)d_in[5];
  const float* fs = (const float*)d_in[6];
  float* outp = (float*)d_out;

  char* ws = (char*)d_ws;
  const size_t xb_bytes = (size_t)MROWS * DMODEL * 2;        // 50,457,600
  const size_t qf_bytes = (size_t)BHN * SEQ * HD * 2;        // 50,380,800
  const size_t kt_bytes = (size_t)BHN * 64 * SEQP * 2;       // 51,904,512
  const size_t wqkvb_bytes = (size_t)3 * DMODEL * DMODEL * 2;
  const size_t woutb_bytes = (size_t)DMODEL * DMODEL * 2;
  const size_t projb_bytes = 8192;
  const size_t ctx_bytes = (size_t)BHN * 64 * 64 * 4;        // 6,291,456
  const size_t ks_bytes = (size_t)BHN * 64 * 4;              // 98,304
  const size_t ctt_bytes = (size_t)BHN * 64 * 64 * 2;        // 3,145,728
  const size_t kst_bytes = (size_t)BHN * 64 * 2;             // 49,152
  const size_t ftab_bytes = (size_t)1040 * 32 * 4;           // 133,120

  bft* xb = (bft*)ws;                                  // X bf16; dead after k_qkv
  bft* qfb = (bft*)(ws + xb_bytes);
  bft* kft = (bft*)(ws + xb_bytes + qf_bytes);         // dead after k_context -> attn
  bft* vt = (bft*)(ws + xb_bytes + qf_bytes + kt_bytes);
  bft* wqkvb = (bft*)(ws + xb_bytes + qf_bytes + 2 * kt_bytes);
  bft* woutb = (bft*)(ws + xb_bytes + qf_bytes + 2 * kt_bytes + wqkvb_bytes);
  bft* projb = (bft*)(ws + xb_bytes + qf_bytes + 2 * kt_bytes + wqkvb_bytes + woutb_bytes);
  float* fcp = (float*)(ws + xb_bytes + qf_bytes + 2 * kt_bytes + wqkvb_bytes + woutb_bytes + projb_bytes);
  float* fsp = (float*)(ws + xb_bytes + qf_bytes + 2 * kt_bytes + wqkvb_bytes + woutb_bytes + projb_bytes + ftab_bytes);

  // aliases into xb region (live only after k_qkv)
  float* ctx = (float*)ws;
  float* ksum = (float*)(ws + ctx_bytes);
  bft* cth = (bft*)(ws + ctx_bytes + ks_bytes);
  bft* ctl = (bft*)(ws + ctx_bytes + ks_bytes + ctt_bytes);
  bft* kth = (bft*)(ws + ctx_bytes + ks_bytes + 2 * ctt_bytes);
  bft* ktl = (bft*)(ws + ctx_bytes + ks_bytes + 2 * ctt_bytes + kst_bytes);
  bft* attn = kft;  // alias kfT region (dead after k_context)

  dim3 blk(256);
  k_cast<<<dim3((MROWS * DMODEL / 4 + 255) / 256), blk, 0, stream>>>(x, xb, MROWS * DMODEL / 4);
  k_cast<<<dim3((3 * DMODEL * DMODEL / 4 + 255) / 256), blk, 0, stream>>>(wqkv, wqkvb, 3 * DMODEL * DMODEL / 4);
  k_cast<<<dim3((DMODEL * DMODEL / 4 + 255) / 256), blk, 0, stream>>>(wout, woutb, DMODEL * DMODEL / 4);
  k_cast<<<dim3((HD * HD / 4 + 255) / 256), blk, 0, stream>>>(proj, projb, HD * HD / 4);
  k_padzero<<<dim3((BHN * 64 + 255) / 256), blk, 0, stream>>>(kft, vt);
  k_ropeprep<<<dim3(130), blk, 0, stream>>>(fc, fs, fcp, fsp);

  k_qkv_gemm<<<dim3(4680), blk, 0, stream>>>(xb, wqkvb, projb, fcp, fsp, qfb, kft, vt);

  // ctx region aliases xb: zero only after k_qkv has consumed X
  hipMemsetAsync(ctx, 0, ctx_bytes + ks_bytes, stream);

  k_context<<<dim3(BHN, 4), blk, 0, stream>>>(kft, vt, ctx, ksum);
  k_ctxprep<<<dim3(BHN), blk, 0, stream>>>(ctx, ksum, cth, ctl, kth, ktl);
  k_qside<<<dim3(BHN, 9), blk, 0, stream>>>(qfb, cth, ctl, kth, ktl, attn);
  k_out_gemm<<<dim3(1542), blk, 0, stream>>>(attn, woutb, bout, outp);
  (void)in_sizes; (void)n_in; (void)out_size; (void)ws_size;
}